// Round 8
// baseline (465.924 us; speedup 1.0000x reference)
//
#include <hip/hip_runtime.h>

#define TAGS 64
#define MAXT 512
#define NEG  -10000.0f
#define CH   8   // feat-staging chunk: steps per LDS buffer

// Kernel 1: bitonic sort of (len, idx) keys, ascending by len.
// perm[0..B) = batch indices sorted by length. One 256-thread block, ~10 us.
__global__ void sort_lens_kernel(const int* __restrict__ lens, int B,
                                 int* __restrict__ perm) {
    __shared__ unsigned s[1024];
    const int tid = threadIdx.x;                      // 256 threads
    for (int i = tid; i < 1024; i += 256) {
        const unsigned l = (i < B) ? (unsigned)lens[i] : 0xFFFFu;
        s[i] = (l << 16) | (unsigned)i;               // len in high bits, idx low
    }
    __syncthreads();
    for (int k = 2; k <= 1024; k <<= 1) {
        for (int j = k >> 1; j > 0; j >>= 1) {
            for (int i = tid; i < 1024; i += 256) {
                const int ixj = i ^ j;
                if (ixj > i) {
                    const unsigned a = s[i], c = s[ixj];
                    if ((a > c) == ((i & k) == 0)) { s[i] = c; s[ixj] = a; }
                }
            }
            __syncthreads();
        }
    }
    for (int i = tid; i < 1024; i += 256)
        if (i < B) perm[i] = (int)(s[i] & 0xFFFFu);
}

// Kernel 2: round-5 step body (best measured), two length-paired batches per
// block (perm[B-1-j] long + perm[j] short => every block ~513 steps), grid
// B/2 = 512, plus DYNAMIC shared memory to force 2 blocks/CU. Rationale:
// rounds 3/5/6 showed per-step time (~1330 cyc) invariant to the instruction
// stream; the suspected limiter is per-CU shared-resource contention (LDS
// pipe: ~205 pipe-cyc/step/wave x 4 single-wave blocks/CU ~ 820 cyc/CU/step).
// Round 7's static-pad throttle was dead-code-eliminated (LDS stayed 38400);
// dynamic shared memory is allocated by launch parameter and cannot be.
__global__ __launch_bounds__(64, 1) void crf_viterbi(
    const float* __restrict__ feats,   // [B, T, K]
    const float* __restrict__ weights, // [K, K] (weights[next][prev])
    const int*   __restrict__ lens,    // [B]
    const int*   __restrict__ perm,    // [B] batches sorted by len (npass==2)
    float*       __restrict__ out,     // [B] scores ++ [B*T] paths (as f32)
    int B, int T, int npass)
{
    extern __shared__ char dyn_throttle[];            // launch-time 18 KB pad
    (void)dyn_throttle;

    const int lane = threadIdx.x;                     // next tag

    __shared__ float fv[TAGS];
    __shared__ float fbuf[2][CH * TAGS];              // 2 x 2 KB feat staging
    __shared__ unsigned char  bptr[MAXT * TAGS];
    __shared__ unsigned short path[MAXT];
    // static ~38.1 KB + 18 KB dynamic = ~56.5 KB -> 2 blocks/CU

    // W row for this lane (as float4 quads), shared by both passes
    float4 w4[16];
    #pragma unroll
    for (int i = 0; i < 16; ++i)
        w4[i] = *reinterpret_cast<const float4*>(weights + lane * TAGS + i * 4);
    const float wEnd = weights[1 * TAGS + lane];      // transition into END

#define F3(a, b, c) fmaxf(fmaxf((a), (b)), (c))
#define M3(a, b, c) min(min((a), (b)), (c))

    for (int pass = 0; pass < npass; ++pass) {
        // paired: long batch first, then its short partner
        const int bb = (npass == 2)
                         ? perm[pass == 0 ? (B - 1 - blockIdx.x) : blockIdx.x]
                         : blockIdx.x;
        const int len = lens[bb];                     // 1..T

        fv[lane] = (lane == 0) ? 0.0f : NEG;          // START = 0

        const float* fb  = feats + (size_t)bb * T * TAGS;
        const int    lim = len * TAGS - 4;            // clamp for tail loads

        float nf = NEG;                               // this lane's running fv

        auto step = [&](int cbuf, int i, int t) {
            const float feat = fbuf[cbuf][i * TAGS + lane];  // off-chain
            float4 fq[16];
            #pragma unroll
            for (int g = 0; g < 16; ++g)
                fq[g] = *reinterpret_cast<const float4*>(&fv[g * 4]);
            float4 c4[16];
            #pragma unroll
            for (int g = 0; g < 16; ++g) {
                c4[g].x = fq[g].x + w4[g].x;
                c4[g].y = fq[g].y + w4[g].y;
                c4[g].z = fq[g].z + w4[g].z;
                c4[g].w = fq[g].w + w4[g].w;
            }
            const float* c = reinterpret_cast<const float*>(c4);

            // value-only max: 3-ary tree (v_max3_f32), depth 4
            float v1[22];
            #pragma unroll
            for (int k = 0; k < 21; ++k) v1[k] = F3(c[3*k], c[3*k+1], c[3*k+2]);
            v1[21] = c[63];
            float v2[8];
            #pragma unroll
            for (int k = 0; k < 7; ++k) v2[k] = F3(v1[3*k], v1[3*k+1], v1[3*k+2]);
            v2[7] = v1[21];
            const float v30 = F3(v2[0], v2[1], v2[2]);
            const float v31 = F3(v2[3], v2[4], v2[5]);
            const float v32 = fmaxf(v2[6], v2[7]);
            const float m   = F3(v30, v31, v32);

            nf = m + feat;                 // emission added after max
            fv[lane] = nf;                 // unblocks step t+1

            // deferred index: first p with c[p]==m (numpy first-occurrence)
            unsigned e[64];
            #pragma unroll
            for (int p = 0; p < 64; ++p) e[p] = (c[p] == m) ? (unsigned)p : 64u;
            unsigned u1[22];
            #pragma unroll
            for (int k = 0; k < 21; ++k) u1[k] = M3(e[3*k], e[3*k+1], e[3*k+2]);
            u1[21] = e[63];
            unsigned u2[8];
            #pragma unroll
            for (int k = 0; k < 7; ++k) u2[k] = M3(u1[3*k], u1[3*k+1], u1[3*k+2]);
            u2[7] = u1[21];
            const unsigned u30 = M3(u2[0], u2[1], u2[2]);
            const unsigned u31 = M3(u2[3], u2[4], u2[5]);
            const unsigned u32 = min(u2[6], u2[7]);
            const unsigned idx = M3(u30, u31, u32);

            bptr[t * TAGS + lane] = (unsigned char)idx;
        };

        // prologue: stage chunk 0 -> fbuf[0]; issue chunk-1 loads
        {
            int o0 = 4 * lane;        if (o0 > lim) o0 = lim;
            int o1 = 256 + 4 * lane;  if (o1 > lim) o1 = lim;
            *reinterpret_cast<float4*>(&fbuf[0][4 * lane])       = *reinterpret_cast<const float4*>(fb + o0);
            *reinterpret_cast<float4*>(&fbuf[0][256 + 4 * lane]) = *reinterpret_cast<const float4*>(fb + o1);
        }
        float4 n0, n1;
        {
            int o0 = CH * TAGS + 4 * lane;        if (o0 > lim) o0 = lim;
            int o1 = CH * TAGS + 256 + 4 * lane;  if (o1 > lim) o1 = lim;
            n0 = *reinterpret_cast<const float4*>(fb + o0);
            n1 = *reinterpret_cast<const float4*>(fb + o1);
        }

        int cb = 0;
        const int nfull = len / CH;
        for (int c = 0; c < nfull; ++c) {
            #pragma unroll
            for (int i = 0; i < CH; ++i) step(cb, i, c * CH + i);
            *reinterpret_cast<float4*>(&fbuf[cb ^ 1][4 * lane])       = n0;
            *reinterpret_cast<float4*>(&fbuf[cb ^ 1][256 + 4 * lane]) = n1;
            {
                int o0 = (c + 2) * CH * TAGS + 4 * lane;        if (o0 > lim) o0 = lim;
                int o1 = (c + 2) * CH * TAGS + 256 + 4 * lane;  if (o1 > lim) o1 = lim;
                n0 = *reinterpret_cast<const float4*>(fb + o0);
                n1 = *reinterpret_cast<const float4*>(fb + o1);
            }
            cb ^= 1;
        }
        const int rem = len - nfull * CH;             // 0..7 remainder steps
        for (int i = 0; i < rem; ++i) step(cb, i, nfull * CH + i);

        // terminal = fv + W[END][prev]; first-max argmax via butterfly
        float tv = nf + wEnd;
        int   ti = lane;
        #pragma unroll
        for (int off = 32; off >= 1; off >>= 1) {
            const float ov = __shfl_xor(tv, off);
            const int   oi = __shfl_xor(ti, off);
            if (ov > tv || (ov == tv && oi < ti)) { tv = ov; ti = oi; }
        }
        if (lane == 0) out[bb] = tv;
        const int bestlast = ti;                      // uniform across lanes

        // padding region: path[t] = bestlast for t in [len-1, T)
        for (int t = lane; t < T; t += 64)
            if (t >= len - 1) path[t] = (unsigned short)bestlast;
        __builtin_amdgcn_wave_barrier();

        // serial chase (lane 0, LDS-resident backpointers)
        if (lane == 0) {
            int tag = bestlast;
            for (int t = len - 1; t >= 1; --t) {
                tag = bptr[t * TAGS + tag];
                path[t - 1] = (unsigned short)tag;
            }
        }
        __builtin_amdgcn_wave_barrier();

        // coalesced path writeback (tags as float32)
        float* pout = out + B + (size_t)bb * T;
        for (int t = lane; t < T; t += 64)
            pout[t] = (float)path[t];
    }
}

extern "C" void kernel_launch(void* const* d_in, const int* in_sizes, int n_in,
                              void* d_out, int out_size, void* d_ws, size_t ws_size,
                              hipStream_t stream) {
    const float* feats   = (const float*)d_in[0];
    const float* weights = (const float*)d_in[1];
    const int*   lens    = (const int*)d_in[2];
    float*       out     = (float*)d_out;
    int*         perm    = (int*)d_ws;

    const int B = in_sizes[2];
    const int T = in_sizes[0] / (B * TAGS);

    const bool paired = (B == 1024) && (ws_size >= 1024 * sizeof(int));
    if (paired) {
        sort_lens_kernel<<<dim3(1), dim3(256), 0, stream>>>(lens, B, perm);
        crf_viterbi<<<dim3(B / 2), dim3(64), 18432, stream>>>(
            feats, weights, lens, perm, out, B, T, 2);
    } else {
        crf_viterbi<<<dim3(B), dim3(64), 18432, stream>>>(
            feats, weights, lens, perm, out, B, T, 1);
    }
}